// Round 1
// baseline (398.576 us; speedup 1.0000x reference)
//
#include <hip/hip_runtime.h>
#include <stdint.h>

typedef unsigned short u16;
typedef __attribute__((ext_vector_type(8))) short short8;
typedef __attribute__((ext_vector_type(4))) float f32x4;
typedef __attribute__((ext_vector_type(2))) float f32x2;

#define N_NODES 100000
#define RREL    3
#define NEDGE   1600000
#define NPAIR   1024
#define NSEG    (RREL * N_NODES)

// binned CSR build params
#define EPB   4096
#define NBLK  ((NEDGE + EPB - 1) / EPB)   // 391
#define DPB   512                          // dsts per bin (dst >> 9)
#define NBIN  ((N_NODES + DPB - 1) / DPB)  // 196
#define LSEG  (DPB * RREL)                 // 1536 local segments per bin

// ---------- bf16 helpers ----------
__device__ __forceinline__ float bflo(unsigned int u) {
    union { unsigned int u; float f; } c; c.u = u << 16; return c.f;
}
__device__ __forceinline__ float bfhi(unsigned int u) {
    union { unsigned int u; float f; } c; c.u = u & 0xffff0000u; return c.f;
}
__device__ __forceinline__ u16 f2bf(float f) {
    union { float f; unsigned int u; } c; c.f = f;
    unsigned int u = c.u;
    u += 0x7fffu + ((u >> 16) & 1u);   // round-to-nearest-even
    return (u16)(u >> 16);
}

// ---------- async global->LDS, 16B per lane ----------
__device__ __forceinline__ void async_copy16(const u16* g, u16* l) {
    __builtin_amdgcn_global_load_lds(
        (const __attribute__((address_space(1))) unsigned int*)g,
        (__attribute__((address_space(3))) unsigned int*)l,
        16, 0, 0);
}

// ---------- cast f32 -> bf16, 4 elems/thread ----------
__global__ __launch_bounds__(256) void cast_kernel(const float* __restrict__ in,
                                                   u16* __restrict__ out, int n4) {
    int i = blockIdx.x * 256 + threadIdx.x;
    if (i >= n4) return;
    float4 v = ((const float4*)in)[i];
    uint2 o;
    o.x = ((unsigned int)f2bf(v.y) << 16) | (unsigned int)f2bf(v.x);
    o.y = ((unsigned int)f2bf(v.w) << 16) | (unsigned int)f2bf(v.z);
    ((uint2*)out)[i] = o;
}

// ========== CSR build: binned counting sort, no global atomics ==========

__global__ __launch_bounds__(256) void p1_count(const int* __restrict__ ed,
                                                int* __restrict__ bc) {
    __shared__ int h[NBIN];
    int t = threadIdx.x, b = blockIdx.x;
    for (int i = t; i < NBIN; i += 256) h[i] = 0;
    __syncthreads();
    int e0 = b * EPB;
    int e1 = e0 + EPB; if (e1 > NEDGE) e1 = NEDGE;
    for (int i = e0 + t; i < e1; i += 256)
        atomicAdd(&h[ed[i] >> 9], 1);
    __syncthreads();
    for (int i = t; i < NBIN; i += 256) bc[i * NBLK + b] = h[i];
}

__global__ __launch_bounds__(512) void p2a_binscan(const int* __restrict__ bc,
                                                   int* __restrict__ sc,
                                                   int* __restrict__ bt) {
    __shared__ int wtot[8];
    int t = threadIdx.x, bin = blockIdx.x;
    int v = (t < NBLK) ? bc[bin * NBLK + t] : 0;
    int lane = t & 63, wv = t >> 6;
    int incl = v;
    #pragma unroll
    for (int d = 1; d < 64; d <<= 1) { int u = __shfl_up(incl, d); if (lane >= d) incl += u; }
    if (lane == 63) wtot[wv] = incl;
    __syncthreads();
    int wpre = 0;
    #pragma unroll
    for (int i = 0; i < 8; ++i) if (i < wv) wpre += wtot[i];
    if (t < NBLK) sc[bin * NBLK + t] = wpre + incl - v;
    if (t == 511) bt[bin] = wpre + incl;
}

__global__ __launch_bounds__(256) void p2b_totscan(const int* __restrict__ bt,
                                                   int* __restrict__ bb) {
    __shared__ int wtot[4];
    int t = threadIdx.x;
    int v = (t < NBIN) ? bt[t] : 0;
    int lane = t & 63, wv = t >> 6;
    int incl = v;
    #pragma unroll
    for (int d = 1; d < 64; d <<= 1) { int u = __shfl_up(incl, d); if (lane >= d) incl += u; }
    if (lane == 63) wtot[wv] = incl;
    __syncthreads();
    int wpre = 0;
    #pragma unroll
    for (int i = 0; i < 4; ++i) if (i < wv) wpre += wtot[i];
    if (t < NBIN) bb[t] = wpre + incl - v;
    if (t == 0) bb[NBIN] = NEDGE;
}

__global__ __launch_bounds__(256) void p3_binscatter(const int* __restrict__ es,
                                                     const int* __restrict__ ed,
                                                     const int* __restrict__ et,
                                                     const int* __restrict__ sc,
                                                     const int* __restrict__ bb,
                                                     unsigned int* __restrict__ binned) {
    __shared__ int pos[NBIN];
    int t = threadIdx.x, b = blockIdx.x;
    for (int i = t; i < NBIN; i += 256) pos[i] = bb[i] + sc[i * NBLK + b];
    __syncthreads();
    int e0 = b * EPB;
    int e1 = e0 + EPB; if (e1 > NEDGE) e1 = NEDGE;
    for (int i = e0 + t; i < e1; i += 256) {
        int d = ed[i];
        int bin = d >> 9;
        unsigned int pk = ((unsigned int)es[i] << 11) | (unsigned int)((d & 511) * 3 + et[i]);
        int p = atomicAdd(&pos[bin], 1);
        binned[p] = pk;
    }
}

__global__ __launch_bounds__(256) void p4_finalize(const unsigned int* __restrict__ binned,
                                                   const int* __restrict__ bb,
                                                   int* __restrict__ seg_start,
                                                   int* __restrict__ cnt,
                                                   int* __restrict__ sorted_src) {
    __shared__ int h[LSEG];
    __shared__ int cur[LSEG];
    __shared__ int wtot4[4];
    int t = threadIdx.x, bin = blockIdx.x;
    for (int i = t; i < LSEG; i += 256) h[i] = 0;
    __syncthreads();
    int eb = bb[bin];
    int ee = bb[bin + 1];
    for (int i = eb + t; i < ee; i += 256)
        atomicAdd(&h[binned[i] & 2047u], 1);
    __syncthreads();
    int i6 = t * 6;
    int s = 0;
    #pragma unroll
    for (int i = 0; i < 6; ++i) s += h[i6 + i];
    int lane = t & 63, wv = t >> 6;
    int incl = s;
    #pragma unroll
    for (int d = 1; d < 64; d <<= 1) { int v = __shfl_up(incl, d); if (lane >= d) incl += v; }
    if (lane == 63) wtot4[wv] = incl;
    __syncthreads();
    int wpre = 0;
    #pragma unroll
    for (int i = 0; i < 4; ++i) if (i < wv) wpre += wtot4[i];
    int run = wpre + incl - s;
    int segbase = bin * LSEG;
    #pragma unroll
    for (int i = 0; i < 6; ++i) {
        int ls = i6 + i;
        int c = h[ls];
        int seg = segbase + ls;
        if (seg < NSEG) { seg_start[seg] = eb + run; cnt[seg] = c; }
        cur[ls] = run;
        run += c;
    }
    __syncthreads();
    for (int i = eb + t; i < ee; i += 256) {
        unsigned int u = binned[i];
        int ls = (int)(u & 2047u);
        int p = atomicAdd(&cur[ls], 1);
        sorted_src[eb + p] = (int)(u >> 11);
    }
}

// ---------- per-segment mean; one QUARTER-WAVE per segment (wave = 4 segs) ----------
// v2: exact-trip-count edge loop (no clamped dup loads, no weight cndmasks),
//     packed f32x2 accumulators (v_pk_add_f32), 2-deep load ILP.
__global__ __launch_bounds__(256) void seg_mean(const uint4* __restrict__ X4,  // (N,16) uint4 = bf16x8
                                                const int* __restrict__ seg_start,
                                                const int* __restrict__ cnt,
                                                const int* __restrict__ sorted_src,
                                                u16* __restrict__ Abuf) {
    int lane = threadIdx.x & 63;
    int q4 = lane >> 4, ql = lane & 15;
    int wid = ((blockIdx.x * 256 + threadIdx.x) >> 6) * 4 + q4;   // NSEG % 4 == 0
    if (wid >= NSEG) return;
    int c  = cnt[wid];
    int st = seg_start[wid];

    f32x2 a0 = {0.f, 0.f}, a1 = {0.f, 0.f}, a2 = {0.f, 0.f}, a3 = {0.f, 0.f};
    const u16* xp = (const u16*)X4 + (size_t)ql * 8;   // per-lane feature base
    int shbase = q4 * 16;

    for (int base = 0; base < c; base += 16) {
        int rem = c - base;                       // >= 1
        int ii  = (ql < rem) ? ql : 0;
        int idxv = sorted_src[st + base + ii];    // idx for edge base+ql (clamped)
        int lim = (rem < 16) ? rem : 16;
        int j = 0;
        for (; j + 2 <= lim; j += 2) {
            int s0 = __shfl(idxv, shbase + j);
            int s1 = __shfl(idxv, shbase + j + 1);
            uint4 v0 = *(const uint4*)(xp + (size_t)s0 * 128);
            uint4 v1 = *(const uint4*)(xp + (size_t)s1 * 128);
            a0 += (f32x2){bflo(v0.x), bfhi(v0.x)};
            a1 += (f32x2){bflo(v0.y), bfhi(v0.y)};
            a2 += (f32x2){bflo(v0.z), bfhi(v0.z)};
            a3 += (f32x2){bflo(v0.w), bfhi(v0.w)};
            a0 += (f32x2){bflo(v1.x), bfhi(v1.x)};
            a1 += (f32x2){bflo(v1.y), bfhi(v1.y)};
            a2 += (f32x2){bflo(v1.z), bfhi(v1.z)};
            a3 += (f32x2){bflo(v1.w), bfhi(v1.w)};
        }
        if (j < lim) {
            int s0 = __shfl(idxv, shbase + j);
            uint4 v0 = *(const uint4*)(xp + (size_t)s0 * 128);
            a0 += (f32x2){bflo(v0.x), bfhi(v0.x)};
            a1 += (f32x2){bflo(v0.y), bfhi(v0.y)};
            a2 += (f32x2){bflo(v0.z), bfhi(v0.z)};
            a3 += (f32x2){bflo(v0.w), bfhi(v0.w)};
        }
    }
    float sc = 1.0f / (float)(c > 0 ? c : 1);
    uint4 o;
    o.x = ((unsigned int)f2bf(a0.y * sc) << 16) | (unsigned int)f2bf(a0.x * sc);
    o.y = ((unsigned int)f2bf(a1.y * sc) << 16) | (unsigned int)f2bf(a1.x * sc);
    o.z = ((unsigned int)f2bf(a2.y * sc) << 16) | (unsigned int)f2bf(a2.x * sc);
    o.w = ((unsigned int)f2bf(a3.y * sc) << 16) | (unsigned int)f2bf(a3.x * sc);
    ((uint4*)Abuf)[(size_t)wid * 16 + ql] = o;
}

// ---------- merged weight transpose: Wt1 (128x512) + Wt2 (64x512), n-major bf16 ----------
__global__ __launch_bounds__(256) void transpose_w_all(const float* __restrict__ Wrel1,
                                                       const float* __restrict__ Wroot1,
                                                       const float* __restrict__ Wrel2,
                                                       const float* __restrict__ Wroot2,
                                                       u16* __restrict__ Wt1,
                                                       u16* __restrict__ Wt2) {
    int idx = blockIdx.x * 256 + threadIdx.x;
    if (idx < 128 * 512) {
        int n = idx >> 9, k = idx & 511;
        float v = (k < 384) ? Wrel1[(size_t)k * 128 + n] : Wroot1[(size_t)(k - 384) * 128 + n];
        Wt1[idx] = f2bf(v);
    } else {
        int j = idx - 128 * 512;
        if (j < 64 * 512) {
            int n = j >> 9, k = j & 511;
            float v = (k < 384) ? Wrel2[(size_t)k * 64 + n] : Wroot2[(size_t)(k - 384) * 64 + n];
            Wt2[j] = f2bf(v);
        }
    }
}

// ---------- fused GEMM: async global_load_lds staging (m97 pattern) ----------
template <int BN, bool RELU, bool OUTF32>
__global__ __launch_bounds__(256) void gemm_fused(const u16* __restrict__ Alo,
                                                  const u16* __restrict__ Ahi,
                                                  const u16* __restrict__ Wt,
                                                  const float* __restrict__ bias,
                                                  void* __restrict__ OutV) {
    constexpr int M = N_NODES;
    constexpr int BM = 128, BK = 32, KTOT = 512, KLO = 384;
    __shared__ __align__(16) u16 As[BM * BK];
    __shared__ __align__(16) u16 Bs[BN * BK];
    const int t = threadIdx.x;
    const int w = t >> 6, l = t & 63;
    const int bm = blockIdx.x * BM;
    constexpr int WN  = (BN == 128) ? 2 : 1;
    constexpr int WTM = (BN == 128) ? 64 : 32;
    constexpr int WTN = 64;
    constexpr int MI = WTM / 16, NI = WTN / 16;
    const int wm = w / WN, wn = w % WN;
    const int q = l >> 4, lm = l & 15;

    f32x4 acc[MI][NI] = {};

    const int ar = t >> 2;            // 0..63
    const int ac = (t & 3) * 8;       // 0,8,16,24
    // LDS dest for thread t in row-major (r*BK+c) layout = 16B * t within each
    // 64-row chunk -> satisfies wave-uniform base + lane*16 requirement.

    // precompute clamped A row pointers (rows fixed across K tiles)
    int gr0 = bm + ar;       if (gr0 >= M) gr0 = M - 1;
    int gr1 = bm + 64 + ar;  if (gr1 >= M) gr1 = M - 1;

    for (int kt = 0; kt < KTOT / BK; ++kt) {
        const int k0 = kt * BK;
        const u16* base; int stride, kk;
        if (k0 < KLO) { base = Alo; stride = 384; kk = k0; }
        else          { base = Ahi; stride = 128; kk = k0 - KLO; }
        __syncthreads();   // previous iteration done reading LDS
        async_copy16(base + (size_t)gr0 * stride + kk + ac, &As[ar * BK + ac]);
        async_copy16(base + (size_t)gr1 * stride + kk + ac, &As[(64 + ar) * BK + ac]);
        #pragma unroll
        for (int i = 0; i < BN / 64; ++i)
            async_copy16(Wt + (size_t)(i * 64 + ar) * KTOT + k0 + ac,
                         &Bs[(i * 64 + ar) * BK + ac]);
        __syncthreads();   // drains vmcnt before LDS reads
        short8 fa[MI], fb[NI];
        #pragma unroll
        for (int mi = 0; mi < MI; ++mi)
            fa[mi] = *(const short8*)&As[(wm * WTM + mi * 16 + lm) * BK + q * 8];
        #pragma unroll
        for (int ni = 0; ni < NI; ++ni)
            fb[ni] = *(const short8*)&Bs[(wn * WTN + ni * 16 + lm) * BK + q * 8];
        #pragma unroll
        for (int mi = 0; mi < MI; ++mi)
            #pragma unroll
            for (int ni = 0; ni < NI; ++ni)
                acc[mi][ni] = __builtin_amdgcn_mfma_f32_16x16x32_bf16(
                    fa[mi], fb[ni], acc[mi][ni], 0, 0, 0);
    }
    // epilogue: C/D layout col=lane&15, row=q*4+reg
    #pragma unroll
    for (int mi = 0; mi < MI; ++mi) {
        #pragma unroll
        for (int ni = 0; ni < NI; ++ni) {
            int gc = wn * WTN + ni * 16 + lm;
            float bv = bias[gc];
            #pragma unroll
            for (int rg = 0; rg < 4; ++rg) {
                int gr = bm + wm * WTM + mi * 16 + q * 4 + rg;
                if (gr < M) {
                    float v = acc[mi][ni][rg] + bv;
                    if (RELU) v = fmaxf(v, 0.0f);
                    if (OUTF32) ((float*)OutV)[(size_t)gr * BN + gc] = v;
                    else        ((u16*)OutV)[(size_t)gr * BN + gc] = f2bf(v);
                }
            }
        }
    }
}

// ---------- final pair MLP ----------
__global__ __launch_bounds__(128) void pair_mlp(const float* __restrict__ node,
                                                const int* __restrict__ nest,
                                                const int* __restrict__ food,
                                                const float* __restrict__ fcW,
                                                const float* __restrict__ fcb,
                                                float* __restrict__ out) {
    int p = blockIdx.x;
    int t = threadIdx.x;
    __shared__ float pv[128];
    int n0 = nest[p], n1 = food[p];
    if ((unsigned)n0 >= (unsigned)N_NODES) n0 = 0;
    if ((unsigned)n1 >= (unsigned)N_NODES) n1 = 0;
    if (t < 64) pv[t] = node[(size_t)n0 * 64 + t];
    else        pv[t] = node[(size_t)n1 * 64 + (t - 64)];
    __syncthreads();
    float s = fcb[t];
    #pragma unroll 4
    for (int k = 0; k < 128; ++k)
        s += pv[k] * fcW[k * 128 + t];
    out[(size_t)p * 128 + t] = tanhf(s);
}

extern "C" void kernel_launch(void* const* d_in, const int* in_sizes, int n_in,
                              void* d_out, int out_size, void* d_ws, size_t ws_size,
                              hipStream_t stream) {
    const float* x    = (const float*)d_in[0];
    const int* esrc   = (const int*)d_in[1];
    const int* edst   = (const int*)d_in[2];
    const int* etyp   = (const int*)d_in[3];
    const int* nest   = (const int*)d_in[5];
    const int* food   = (const int*)d_in[6];
    const float* Wrel1  = (const float*)d_in[7];
    const float* Wroot1 = (const float*)d_in[8];
    const float* b1     = (const float*)d_in[9];
    const float* Wrel2  = (const float*)d_in[10];
    const float* Wroot2 = (const float*)d_in[11];
    const float* b2     = (const float*)d_in[12];
    const float* fcW    = (const float*)d_in[13];
    const float* fcb    = (const float*)d_in[14];
    float* out = (float*)d_out;

    char* ws = (char*)d_ws;
    size_t off = 0;
    auto alloc_b = [&](size_t bytes) -> void* {
        void* p = ws + off;
        off += (bytes + 255) & ~(size_t)255;
        return p;
    };
    int* bc          = (int*)alloc_b((size_t)NBIN * NBLK * 4);
    int* sc          = (int*)alloc_b((size_t)NBIN * NBLK * 4);
    int* bt          = (int*)alloc_b((size_t)NBIN * 4);
    int* bb          = (int*)alloc_b((size_t)(NBIN + 1) * 4);
    unsigned int* bn = (unsigned int*)alloc_b((size_t)NEDGE * 4);
    int* seg_start   = (int*)alloc_b((size_t)NSEG * 4);
    int* cnt         = (int*)alloc_b((size_t)NSEG * 4);
    int* sorted_src  = (int*)alloc_b((size_t)NEDGE * 4);
    u16* Wt1         = (u16*)alloc_b((size_t)128 * 512 * 2);
    u16* Wt2         = (u16*)alloc_b((size_t)64 * 512 * 2);
    u16* xb          = (u16*)alloc_b((size_t)N_NODES * 128 * 2);
    u16* Abuf        = (u16*)alloc_b((size_t)N_NODES * 384 * 2);
    u16* h1          = (u16*)alloc_b((size_t)N_NODES * 128 * 2);
    float* node      = (float*)alloc_b((size_t)N_NODES * 64 * 4);

    // CSR build: binned counting sort (no global atomics)
    p1_count<<<NBLK, 256, 0, stream>>>(edst, bc);
    p2a_binscan<<<NBIN, 512, 0, stream>>>(bc, sc, bt);
    p2b_totscan<<<1, 256, 0, stream>>>(bt, bb);
    p3_binscatter<<<NBLK, 256, 0, stream>>>(esrc, edst, etyp, sc, bb, bn);
    p4_finalize<<<NBIN, 256, 0, stream>>>(bn, bb, seg_start, cnt, sorted_src);

    // merged weight transpose (f32 -> bf16 n-major)
    transpose_w_all<<<(192 * 512) / 256, 256, 0, stream>>>(Wrel1, Wroot1, Wrel2, Wroot2, Wt1, Wt2);

    // cast x -> bf16 (gather source for layer-1 aggregation + GEMM A)
    cast_kernel<<<(N_NODES * 128 / 4 + 255) / 256, 256, 0, stream>>>(x, xb, N_NODES * 128 / 4);

    const int segBlocks  = NSEG / 16;                    // 18750 (4 segs/wave, 4 waves/block)
    const int gemmBlocks = (N_NODES + 127) / 128;        // 782

    // layer 1
    seg_mean<<<segBlocks, 256, 0, stream>>>((const uint4*)xb, seg_start, cnt, sorted_src, Abuf);
    gemm_fused<128, true, false><<<gemmBlocks, 256, 0, stream>>>(Abuf, xb, Wt1, b1, h1);

    // layer 2
    seg_mean<<<segBlocks, 256, 0, stream>>>((const uint4*)h1, seg_start, cnt, sorted_src, Abuf);
    gemm_fused<64, false, true><<<gemmBlocks, 256, 0, stream>>>(Abuf, h1, Wt2, b2, node);

    // pair MLP (f32)
    pair_mlp<<<NPAIR, 128, 0, stream>>>(node, nest, food, fcW, fcb, out);
}

// Round 2
// 396.950 us; speedup vs baseline: 1.0041x; 1.0041x over previous
//
#include <hip/hip_runtime.h>
#include <stdint.h>

typedef unsigned short u16;
typedef __attribute__((ext_vector_type(8))) short short8;
typedef __attribute__((ext_vector_type(4))) float f32x4;
typedef __attribute__((ext_vector_type(2))) float f32x2;

#define N_NODES 100000
#define RREL    3
#define NEDGE   1600000
#define NPAIR   1024
#define NSEG    (RREL * N_NODES)

// binned CSR build params
#define EPB   4096
#define NBLK  ((NEDGE + EPB - 1) / EPB)   // 391
#define DPB   512                          // dsts per bin (dst >> 9)
#define NBIN  ((N_NODES + DPB - 1) / DPB)  // 196
#define LSEG  (DPB * RREL)                 // 1536 local segments per bin

// ---------- bf16 helpers ----------
__device__ __forceinline__ float bflo(unsigned int u) {
    union { unsigned int u; float f; } c; c.u = u << 16; return c.f;
}
__device__ __forceinline__ float bfhi(unsigned int u) {
    union { unsigned int u; float f; } c; c.u = u & 0xffff0000u; return c.f;
}
__device__ __forceinline__ u16 f2bf(float f) {
    union { float f; unsigned int u; } c; c.f = f;
    unsigned int u = c.u;
    u += 0x7fffu + ((u >> 16) & 1u);   // round-to-nearest-even
    return (u16)(u >> 16);
}

// ---------- async global->LDS, 16B per lane ----------
__device__ __forceinline__ void async_copy16(const u16* g, u16* l) {
    __builtin_amdgcn_global_load_lds(
        (const __attribute__((address_space(1))) unsigned int*)g,
        (__attribute__((address_space(3))) unsigned int*)l,
        16, 0, 0);
}

// ---------- cast f32 -> bf16, 4 elems/thread ----------
__global__ __launch_bounds__(256) void cast_kernel(const float* __restrict__ in,
                                                   u16* __restrict__ out, int n4) {
    int i = blockIdx.x * 256 + threadIdx.x;
    if (i >= n4) return;
    float4 v = ((const float4*)in)[i];
    uint2 o;
    o.x = ((unsigned int)f2bf(v.y) << 16) | (unsigned int)f2bf(v.x);
    o.y = ((unsigned int)f2bf(v.w) << 16) | (unsigned int)f2bf(v.z);
    ((uint2*)out)[i] = o;
}

// ========== CSR build: binned counting sort, no global atomics ==========

__global__ __launch_bounds__(256) void p1_count(const int* __restrict__ ed,
                                                int* __restrict__ bc) {
    __shared__ int h[NBIN];
    int t = threadIdx.x, b = blockIdx.x;
    for (int i = t; i < NBIN; i += 256) h[i] = 0;
    __syncthreads();
    int e0 = b * EPB;
    int e1 = e0 + EPB; if (e1 > NEDGE) e1 = NEDGE;
    for (int i = e0 + t; i < e1; i += 256)
        atomicAdd(&h[ed[i] >> 9], 1);
    __syncthreads();
    for (int i = t; i < NBIN; i += 256) bc[i * NBLK + b] = h[i];
}

__global__ __launch_bounds__(512) void p2a_binscan(const int* __restrict__ bc,
                                                   int* __restrict__ sc,
                                                   int* __restrict__ bt) {
    __shared__ int wtot[8];
    int t = threadIdx.x, bin = blockIdx.x;
    int v = (t < NBLK) ? bc[bin * NBLK + t] : 0;
    int lane = t & 63, wv = t >> 6;
    int incl = v;
    #pragma unroll
    for (int d = 1; d < 64; d <<= 1) { int u = __shfl_up(incl, d); if (lane >= d) incl += u; }
    if (lane == 63) wtot[wv] = incl;
    __syncthreads();
    int wpre = 0;
    #pragma unroll
    for (int i = 0; i < 8; ++i) if (i < wv) wpre += wtot[i];
    if (t < NBLK) sc[bin * NBLK + t] = wpre + incl - v;
    if (t == 511) bt[bin] = wpre + incl;
}

__global__ __launch_bounds__(256) void p2b_totscan(const int* __restrict__ bt,
                                                   int* __restrict__ bb) {
    __shared__ int wtot[4];
    int t = threadIdx.x;
    int v = (t < NBIN) ? bt[t] : 0;
    int lane = t & 63, wv = t >> 6;
    int incl = v;
    #pragma unroll
    for (int d = 1; d < 64; d <<= 1) { int u = __shfl_up(incl, d); if (lane >= d) incl += u; }
    if (lane == 63) wtot[wv] = incl;
    __syncthreads();
    int wpre = 0;
    #pragma unroll
    for (int i = 0; i < 4; ++i) if (i < wv) wpre += wtot[i];
    if (t < NBIN) bb[t] = wpre + incl - v;
    if (t == 0) bb[NBIN] = NEDGE;
}

__global__ __launch_bounds__(256) void p3_binscatter(const int* __restrict__ es,
                                                     const int* __restrict__ ed,
                                                     const int* __restrict__ et,
                                                     const int* __restrict__ sc,
                                                     const int* __restrict__ bb,
                                                     unsigned int* __restrict__ binned) {
    __shared__ int pos[NBIN];
    int t = threadIdx.x, b = blockIdx.x;
    for (int i = t; i < NBIN; i += 256) pos[i] = bb[i] + sc[i * NBLK + b];
    __syncthreads();
    int e0 = b * EPB;
    int e1 = e0 + EPB; if (e1 > NEDGE) e1 = NEDGE;
    for (int i = e0 + t; i < e1; i += 256) {
        int d = ed[i];
        int bin = d >> 9;
        unsigned int pk = ((unsigned int)es[i] << 11) | (unsigned int)((d & 511) * 3 + et[i]);
        int p = atomicAdd(&pos[bin], 1);
        binned[p] = pk;
    }
}

__global__ __launch_bounds__(256) void p4_finalize(const unsigned int* __restrict__ binned,
                                                   const int* __restrict__ bb,
                                                   int* __restrict__ seg_start,
                                                   int* __restrict__ cnt,
                                                   int* __restrict__ sorted_src) {
    __shared__ int h[LSEG];
    __shared__ int cur[LSEG];
    __shared__ int wtot4[4];
    int t = threadIdx.x, bin = blockIdx.x;
    for (int i = t; i < LSEG; i += 256) h[i] = 0;
    __syncthreads();
    int eb = bb[bin];
    int ee = bb[bin + 1];
    for (int i = eb + t; i < ee; i += 256)
        atomicAdd(&h[binned[i] & 2047u], 1);
    __syncthreads();
    int i6 = t * 6;
    int s = 0;
    #pragma unroll
    for (int i = 0; i < 6; ++i) s += h[i6 + i];
    int lane = t & 63, wv = t >> 6;
    int incl = s;
    #pragma unroll
    for (int d = 1; d < 64; d <<= 1) { int v = __shfl_up(incl, d); if (lane >= d) incl += v; }
    if (lane == 63) wtot4[wv] = incl;
    __syncthreads();
    int wpre = 0;
    #pragma unroll
    for (int i = 0; i < 4; ++i) if (i < wv) wpre += wtot4[i];
    int run = wpre + incl - s;
    int segbase = bin * LSEG;
    #pragma unroll
    for (int i = 0; i < 6; ++i) {
        int ls = i6 + i;
        int c = h[ls];
        int seg = segbase + ls;
        if (seg < NSEG) { seg_start[seg] = eb + run; cnt[seg] = c; }
        cur[ls] = run;
        run += c;
    }
    __syncthreads();
    for (int i = eb + t; i < ee; i += 256) {
        unsigned int u = binned[i];
        int ls = (int)(u & 2047u);
        int p = atomicAdd(&cur[ls], 1);
        sorted_src[eb + p] = (int)(u >> 11);
    }
}

// ---------- layer-1 per-segment mean; one QUARTER-WAVE per segment ----------
__global__ __launch_bounds__(256) void seg_mean(const uint4* __restrict__ X4,  // (N,16) uint4 = bf16x8
                                                const int* __restrict__ seg_start,
                                                const int* __restrict__ cnt,
                                                const int* __restrict__ sorted_src,
                                                u16* __restrict__ Abuf) {
    int lane = threadIdx.x & 63;
    int q4 = lane >> 4, ql = lane & 15;
    int wid = ((blockIdx.x * 256 + threadIdx.x) >> 6) * 4 + q4;   // NSEG % 4 == 0
    if (wid >= NSEG) return;
    int c  = cnt[wid];
    int st = seg_start[wid];

    f32x2 a0 = {0.f, 0.f}, a1 = {0.f, 0.f}, a2 = {0.f, 0.f}, a3 = {0.f, 0.f};
    const u16* xp = (const u16*)X4 + (size_t)ql * 8;   // per-lane feature base
    int shbase = q4 * 16;

    for (int base = 0; base < c; base += 16) {
        int rem = c - base;                       // >= 1
        int ii  = (ql < rem) ? ql : 0;
        int idxv = sorted_src[st + base + ii];    // idx for edge base+ql (clamped)
        int lim = (rem < 16) ? rem : 16;
        int j = 0;
        for (; j + 2 <= lim; j += 2) {
            int s0 = __shfl(idxv, shbase + j);
            int s1 = __shfl(idxv, shbase + j + 1);
            uint4 v0 = *(const uint4*)(xp + (size_t)s0 * 128);
            uint4 v1 = *(const uint4*)(xp + (size_t)s1 * 128);
            a0 += (f32x2){bflo(v0.x), bfhi(v0.x)};
            a1 += (f32x2){bflo(v0.y), bfhi(v0.y)};
            a2 += (f32x2){bflo(v0.z), bfhi(v0.z)};
            a3 += (f32x2){bflo(v0.w), bfhi(v0.w)};
            a0 += (f32x2){bflo(v1.x), bfhi(v1.x)};
            a1 += (f32x2){bflo(v1.y), bfhi(v1.y)};
            a2 += (f32x2){bflo(v1.z), bfhi(v1.z)};
            a3 += (f32x2){bflo(v1.w), bfhi(v1.w)};
        }
        if (j < lim) {
            int s0 = __shfl(idxv, shbase + j);
            uint4 v0 = *(const uint4*)(xp + (size_t)s0 * 128);
            a0 += (f32x2){bflo(v0.x), bfhi(v0.x)};
            a1 += (f32x2){bflo(v0.y), bfhi(v0.y)};
            a2 += (f32x2){bflo(v0.z), bfhi(v0.z)};
            a3 += (f32x2){bflo(v0.w), bfhi(v0.w)};
        }
    }
    float sc = 1.0f / (float)(c > 0 ? c : 1);
    uint4 o;
    o.x = ((unsigned int)f2bf(a0.y * sc) << 16) | (unsigned int)f2bf(a0.x * sc);
    o.y = ((unsigned int)f2bf(a1.y * sc) << 16) | (unsigned int)f2bf(a1.x * sc);
    o.z = ((unsigned int)f2bf(a2.y * sc) << 16) | (unsigned int)f2bf(a2.x * sc);
    o.w = ((unsigned int)f2bf(a3.y * sc) << 16) | (unsigned int)f2bf(a3.x * sc);
    ((uint4*)Abuf)[(size_t)wid * 16 + ql] = o;
}

// ---------- layer-2 fused per-dst aggregation: node = root + sum_r mean_r(P_r) ----------
// one QUARTER-WAVE per dst; 8 lanes x 16B per edge-row (128B = 1 cacheline), 2 edge slots
__global__ __launch_bounds__(256) void seg_sum2(const u16* __restrict__ P,       // (N,192) bf16, row stride 192
                                                const int* __restrict__ seg_start,
                                                const int* __restrict__ cnt,
                                                const int* __restrict__ sorted_src,
                                                float* __restrict__ node) {      // (N,64) f32, root preloaded
    int lane = threadIdx.x & 63;
    int q4 = lane >> 4, ql = lane & 15;
    int e  = ql >> 3;            // edge slot 0/1
    int fl = ql & 7;             // feature chunk (8 feats = 16B)
    int dst = ((blockIdx.x * 256 + threadIdx.x) >> 6) * 4 + q4;   // N_NODES % 4 == 0
    if (dst >= N_NODES) return;
    int shbase = q4 * 16;

    // root (f32) preloaded by GEMM epilogue
    const float* np = node + (size_t)dst * 64 + fl * 8;
    float4 r0 = *(const float4*)np;
    float4 r1 = *(const float4*)(np + 4);
    f32x2 d0 = {r0.x, r0.y}, d1 = {r0.z, r0.w};
    f32x2 d2 = {r1.x, r1.y}, d3 = {r1.z, r1.w};

    int c3[3], st3[3];
    #pragma unroll
    for (int r = 0; r < 3; ++r) { c3[r] = cnt[dst * 3 + r]; st3[r] = seg_start[dst * 3 + r]; }

    #pragma unroll
    for (int r = 0; r < 3; ++r) {
        int c = c3[r], st = st3[r];
        f32x2 s0 = {0.f,0.f}, s1 = {0.f,0.f}, s2 = {0.f,0.f}, s3 = {0.f,0.f};
        for (int base = 0; base < c; base += 16) {
            int rem = c - base;
            int ii  = (ql < rem) ? ql : 0;
            int idxv = sorted_src[st + base + ii];
            int lim = (rem < 16) ? rem : 16;
            for (int j = 0; j < lim; j += 2) {
                int jj = j + e;
                bool act = jj < lim;
                int sidx = __shfl(idxv, shbase + (act ? jj : 0));
                if (act) {
                    uint4 v = *(const uint4*)(P + (size_t)sidx * 192 + r * 64 + fl * 8);
                    s0 += (f32x2){bflo(v.x), bfhi(v.x)};
                    s1 += (f32x2){bflo(v.y), bfhi(v.y)};
                    s2 += (f32x2){bflo(v.z), bfhi(v.z)};
                    s3 += (f32x2){bflo(v.w), bfhi(v.w)};
                }
            }
        }
        // combine edge slots (lane l <-> l^8), both halves end with full sum
        s0.x += __shfl_xor(s0.x, 8); s0.y += __shfl_xor(s0.y, 8);
        s1.x += __shfl_xor(s1.x, 8); s1.y += __shfl_xor(s1.y, 8);
        s2.x += __shfl_xor(s2.x, 8); s2.y += __shfl_xor(s2.y, 8);
        s3.x += __shfl_xor(s3.x, 8); s3.y += __shfl_xor(s3.y, 8);
        float sc = (c > 0) ? (1.0f / (float)c) : 0.0f;
        f32x2 scv = {sc, sc};
        d0 += scv * s0; d1 += scv * s1; d2 += scv * s2; d3 += scv * s3;
    }
    if (e == 0) {
        float4 o0 = {d0.x, d0.y, d1.x, d1.y};
        float4 o1 = {d2.x, d2.y, d3.x, d3.y};
        *(float4*)(node + (size_t)dst * 64 + fl * 8)     = o0;
        *(float4*)(node + (size_t)dst * 64 + fl * 8 + 4) = o1;
    }
}

// ---------- merged weight transpose: Wt1 (128n x 512k) + Wt2 (256n x 128k), n-major bf16 ----------
__global__ __launch_bounds__(256) void transpose_w_all(const float* __restrict__ Wrel1,
                                                       const float* __restrict__ Wroot1,
                                                       const float* __restrict__ Wrel2,
                                                       const float* __restrict__ Wroot2,
                                                       u16* __restrict__ Wt1,
                                                       u16* __restrict__ Wt2) {
    int idx = blockIdx.x * 256 + threadIdx.x;
    if (idx < 128 * 512) {
        int n = idx >> 9, k = idx & 511;
        float v = (k < 384) ? Wrel1[(size_t)k * 128 + n] : Wroot1[(size_t)(k - 384) * 128 + n];
        Wt1[idx] = f2bf(v);
    } else {
        int j = idx - 128 * 512;
        if (j < 256 * 128) {
            int n = j >> 7, k = j & 127;
            // n<192: rel r=n>>6, emb e=n&63 -> Wrel2[r][k][e];  n>=192: Wroot2[k][n-192]
            float v = (n < 192) ? Wrel2[((size_t)(n >> 6) * 128 + k) * 64 + (n & 63)]
                                : Wroot2[(size_t)k * 64 + (n - 192)];
            Wt2[j] = f2bf(v);
        }
    }
}

// ---------- fused GEMM: async global_load_lds staging (m97 pattern) ----------
// OMODE 0: bf16 out stride BN (+bias, opt relu)
// OMODE 1: f32  out stride BN (+bias)
// OMODE 2: split -- cols<192 bf16 -> Out (stride 192, no bias); cols>=192 f32+bias -> Out2 (stride 64)
template <int BM, int BN, int KTOT, int KLO, bool RELU, int OMODE>
__global__ __launch_bounds__(256) void gemm_fused(const u16* __restrict__ Alo,
                                                  const u16* __restrict__ Ahi,
                                                  const u16* __restrict__ Wt,
                                                  const float* __restrict__ bias,
                                                  void* __restrict__ OutV,
                                                  float* __restrict__ Out2) {
    constexpr int M = N_NODES;
    constexpr int BK = 32;
    __shared__ __align__(16) u16 As[BM * BK];
    __shared__ __align__(16) u16 Bs[BN * BK];
    const int t = threadIdx.x;
    const int w = t >> 6, l = t & 63;
    const int bm = blockIdx.x * BM;
    constexpr int WN  = BN / 64;          // waves along N
    constexpr int WM  = 4 / WN;           // waves along M
    constexpr int WTM = BM / WM;
    constexpr int WTN = 64;
    constexpr int MI = WTM / 16, NI = WTN / 16;
    const int wm = w / WN, wn = w % WN;
    const int q = l >> 4, lm = l & 15;

    f32x4 acc[MI][NI] = {};

    const int ar = t >> 2;            // 0..63
    const int ac = (t & 3) * 8;       // 0,8,16,24

    int gr0 = bm + ar;       if (gr0 >= M) gr0 = M - 1;
    int gr1 = bm + 64 + ar;  if (gr1 >= M) gr1 = M - 1;

    for (int kt = 0; kt < KTOT / BK; ++kt) {
        const int k0 = kt * BK;
        const u16* base; int stride, kk;
        if (k0 < KLO) { base = Alo; stride = KLO == KTOT ? KTOT : 384; kk = k0; }
        else          { base = Ahi; stride = 128; kk = k0 - KLO; }
        __syncthreads();   // previous iteration done reading LDS
        async_copy16(base + (size_t)gr0 * stride + kk + ac, &As[ar * BK + ac]);
        if (BM == 128)
            async_copy16(base + (size_t)gr1 * stride + kk + ac, &As[(64 + ar) * BK + ac]);
        #pragma unroll
        for (int i = 0; i < BN / 64; ++i)
            async_copy16(Wt + (size_t)(i * 64 + ar) * KTOT + k0 + ac,
                         &Bs[(i * 64 + ar) * BK + ac]);
        __syncthreads();   // drains vmcnt before LDS reads
        short8 fa[MI], fb[NI];
        #pragma unroll
        for (int mi = 0; mi < MI; ++mi)
            fa[mi] = *(const short8*)&As[(wm * WTM + mi * 16 + lm) * BK + q * 8];
        #pragma unroll
        for (int ni = 0; ni < NI; ++ni)
            fb[ni] = *(const short8*)&Bs[(wn * WTN + ni * 16 + lm) * BK + q * 8];
        #pragma unroll
        for (int mi = 0; mi < MI; ++mi)
            #pragma unroll
            for (int ni = 0; ni < NI; ++ni)
                acc[mi][ni] = __builtin_amdgcn_mfma_f32_16x16x32_bf16(
                    fa[mi], fb[ni], acc[mi][ni], 0, 0, 0);
    }
    // epilogue: C/D layout col=lane&15, row=q*4+reg
    #pragma unroll
    for (int mi = 0; mi < MI; ++mi) {
        #pragma unroll
        for (int ni = 0; ni < NI; ++ni) {
            int gc = wn * WTN + ni * 16 + lm;
            float bv;
            if (OMODE == 2) bv = (gc >= 192) ? bias[gc - 192] : 0.0f;
            else            bv = bias[gc];
            #pragma unroll
            for (int rg = 0; rg < 4; ++rg) {
                int gr = bm + wm * WTM + mi * 16 + q * 4 + rg;
                if (gr < M) {
                    float v = acc[mi][ni][rg] + bv;
                    if (RELU) v = fmaxf(v, 0.0f);
                    if (OMODE == 0)      ((u16*)OutV)[(size_t)gr * BN + gc] = f2bf(v);
                    else if (OMODE == 1) ((float*)OutV)[(size_t)gr * BN + gc] = v;
                    else {
                        if (gc < 192) ((u16*)OutV)[(size_t)gr * 192 + gc] = f2bf(v);
                        else          Out2[(size_t)gr * 64 + (gc - 192)] = v;
                    }
                }
            }
        }
    }
}

// ---------- final pair MLP ----------
__global__ __launch_bounds__(128) void pair_mlp(const float* __restrict__ node,
                                                const int* __restrict__ nest,
                                                const int* __restrict__ food,
                                                const float* __restrict__ fcW,
                                                const float* __restrict__ fcb,
                                                float* __restrict__ out) {
    int p = blockIdx.x;
    int t = threadIdx.x;
    __shared__ float pv[128];
    int n0 = nest[p], n1 = food[p];
    if ((unsigned)n0 >= (unsigned)N_NODES) n0 = 0;
    if ((unsigned)n1 >= (unsigned)N_NODES) n1 = 0;
    if (t < 64) pv[t] = node[(size_t)n0 * 64 + t];
    else        pv[t] = node[(size_t)n1 * 64 + (t - 64)];
    __syncthreads();
    float s = fcb[t];
    #pragma unroll 4
    for (int k = 0; k < 128; ++k)
        s += pv[k] * fcW[k * 128 + t];
    out[(size_t)p * 128 + t] = tanhf(s);
}

extern "C" void kernel_launch(void* const* d_in, const int* in_sizes, int n_in,
                              void* d_out, int out_size, void* d_ws, size_t ws_size,
                              hipStream_t stream) {
    const float* x    = (const float*)d_in[0];
    const int* esrc   = (const int*)d_in[1];
    const int* edst   = (const int*)d_in[2];
    const int* etyp   = (const int*)d_in[3];
    const int* nest   = (const int*)d_in[5];
    const int* food   = (const int*)d_in[6];
    const float* Wrel1  = (const float*)d_in[7];
    const float* Wroot1 = (const float*)d_in[8];
    const float* b1     = (const float*)d_in[9];
    const float* Wrel2  = (const float*)d_in[10];
    const float* Wroot2 = (const float*)d_in[11];
    const float* b2     = (const float*)d_in[12];
    const float* fcW    = (const float*)d_in[13];
    const float* fcb    = (const float*)d_in[14];
    float* out = (float*)d_out;

    char* ws = (char*)d_ws;
    size_t off = 0;
    auto alloc_b = [&](size_t bytes) -> void* {
        void* p = ws + off;
        off += (bytes + 255) & ~(size_t)255;
        return p;
    };
    int* bc          = (int*)alloc_b((size_t)NBIN * NBLK * 4);
    int* sc          = (int*)alloc_b((size_t)NBIN * NBLK * 4);
    int* bt          = (int*)alloc_b((size_t)NBIN * 4);
    int* bb          = (int*)alloc_b((size_t)(NBIN + 1) * 4);
    unsigned int* bn = (unsigned int*)alloc_b((size_t)NEDGE * 4);
    int* seg_start   = (int*)alloc_b((size_t)NSEG * 4);
    int* cnt         = (int*)alloc_b((size_t)NSEG * 4);
    int* sorted_src  = (int*)alloc_b((size_t)NEDGE * 4);
    u16* Wt1         = (u16*)alloc_b((size_t)128 * 512 * 2);
    u16* Wt2         = (u16*)alloc_b((size_t)256 * 128 * 2);
    u16* xb          = (u16*)alloc_b((size_t)N_NODES * 128 * 2);
    u16* Abuf        = (u16*)alloc_b((size_t)N_NODES * 384 * 2);   // also reused as P (N,192)
    u16* h1          = (u16*)alloc_b((size_t)N_NODES * 128 * 2);
    float* node      = (float*)alloc_b((size_t)N_NODES * 64 * 4);
    u16* P           = Abuf;   // layer-2 transformed features, (N,192) bf16

    // CSR build: binned counting sort (no global atomics)
    p1_count<<<NBLK, 256, 0, stream>>>(edst, bc);
    p2a_binscan<<<NBIN, 512, 0, stream>>>(bc, sc, bt);
    p2b_totscan<<<1, 256, 0, stream>>>(bt, bb);
    p3_binscatter<<<NBLK, 256, 0, stream>>>(esrc, edst, etyp, sc, bb, bn);
    p4_finalize<<<NBIN, 256, 0, stream>>>(bn, bb, seg_start, cnt, sorted_src);

    // merged weight transpose (f32 -> bf16 n-major)
    transpose_w_all<<<(128 * 512 + 256 * 128 + 255) / 256, 256, 0, stream>>>(
        Wrel1, Wroot1, Wrel2, Wroot2, Wt1, Wt2);

    // cast x -> bf16 (gather source for layer-1 aggregation + GEMM A)
    cast_kernel<<<(N_NODES * 128 / 4 + 255) / 256, 256, 0, stream>>>(x, xb, N_NODES * 128 / 4);

    const int segBlocks   = NSEG / 16;                    // 18750 (4 segs/wave, 4 waves/block)
    const int gemmBlocks1 = (N_NODES + 127) / 128;        // 782
    const int gemmBlocks2 = (N_NODES + 63) / 64;          // 1563
    const int dstBlocks   = N_NODES / 16;                 // 6250 (4 dsts/wave, 4 waves/block)

    // layer 1: aggregate-then-transform (F==H, no width win from reordering)
    seg_mean<<<segBlocks, 256, 0, stream>>>((const uint4*)xb, seg_start, cnt, sorted_src, Abuf);
    gemm_fused<128, 128, 512, 384, true, 0><<<gemmBlocks1, 256, 0, stream>>>(
        Abuf, xb, Wt1, b1, h1, nullptr);

    // layer 2: transform-then-aggregate (gather 128B instead of 256B per edge)
    // P = h1 @ [Wrel2_0 | Wrel2_1 | Wrel2_2] (bf16), node = h1 @ Wroot2 + b2 (f32)
    gemm_fused<64, 256, 128, 128, false, 2><<<gemmBlocks2, 256, 0, stream>>>(
        h1, h1, Wt2, b2, P, node);
    seg_sum2<<<dstBlocks, 256, 0, stream>>>(P, seg_start, cnt, sorted_src, node);

    // pair MLP (f32)
    pair_mlp<<<NPAIR, 128, 0, stream>>>(node, nest, food, fcW, fcb, out);
}